// Round 6
// baseline (637.165 us; speedup 1.0000x reference)
//
#include <hip/hip_runtime.h>

// GNN: 2 x (SimpleConv(mean, cat) -> Linear(256->128) -> ReLU)
// N=50000 nodes, E=640000 edges, H=128.
//
// R1-R14: CSR pipeline, bf16, MFMA gemm, 5 kernels + memset. 209.7us.
// R15: slice-major [4][N][32]; agg FETCH compulsory but VALU-bound. 310.
// R16: quad-per-node serial gather. 221.4. R17: fill single-pass REGRESSED;
//      agg 8-deep batches. 215.5. R18: fill partition + upfront loads; agg
//      sw-pipeline. 214.2.
// R19 ACCOUNTING: total - sum(kernels) = ~77us consistent across R15-R17 ->
//      36% of wall is 6-dispatch serialization (~13us/gap). FIX = single
//      persistent kernel.
// R20 FAILED: hipLaunchCooperativeKernel (+occupancy query) inside the
//      harness's graph-capturing stream -> capture invalidated, bench died.
// R21: same mega-kernel, capture-proof: plain <<<512,256>>> launch,
//      __launch_bounds__(256,2) guarantees 2 blocks/CU co-residency (LDS
//      9.3KB, W streamed from L2 in wave-coalesced Wsw layout), hand-rolled
//      generation grid barrier (device-scope atomics + threadfence), and
//      work-stealing unit queues (one atomic counter per phase; fill grabs
//      chunks of 8) to kill the 2-vs-1.53-unit straggler tail that static
//      striding would give 512 blocks on 782 units.

#define HDIM 128
#define CAP 32            // padded CSR slots/node; P(deg>32 | Poisson 12.8) ~ 2e-6
#define FCH 2048          // edges per fill chunk
#define NBLK 512          // persistent blocks = 2/CU x 256 CUs (guaranteed resident)

typedef __bf16 bf16x8 __attribute__((ext_vector_type(8)));
typedef float floatx4 __attribute__((ext_vector_type(4)));

__device__ __forceinline__ unsigned short f2bf(float f) {
    unsigned int u = __float_as_uint(f);
    unsigned int r = (u + 0x7fff + ((u >> 16) & 1)) >> 16;   // RNE
    return (unsigned short)r;
}
__device__ __forceinline__ float bf2f(unsigned short b) {
    return __uint_as_float((unsigned int)b << 16);
}
__device__ __forceinline__ void acc8(const uint4& u, float a, float* s) {
    s[0] = fmaf(bf2f((unsigned short)(u.x & 0xffff)), a, s[0]);
    s[1] = fmaf(bf2f((unsigned short)(u.x >> 16)), a, s[1]);
    s[2] = fmaf(bf2f((unsigned short)(u.y & 0xffff)), a, s[2]);
    s[3] = fmaf(bf2f((unsigned short)(u.y >> 16)), a, s[3]);
    s[4] = fmaf(bf2f((unsigned short)(u.z & 0xffff)), a, s[4]);
    s[5] = fmaf(bf2f((unsigned short)(u.z >> 16)), a, s[5]);
    s[6] = fmaf(bf2f((unsigned short)(u.w & 0xffff)), a, s[6]);
    s[7] = fmaf(bf2f((unsigned short)(u.w >> 16)), a, s[7]);
}

// Generation grid barrier. All NBLK blocks call this the same number of
// times. Count+gen in device memory (zeroed by host memset each launch).
// Device-scope atomics reach the coherence point past per-XCD L2s;
// __threadfence on both sides orders/flushes normal loads/stores.
__device__ __forceinline__ void grid_sync(int* cnt, int* gen) {
    __syncthreads();
    if (threadIdx.x == 0) {
        __threadfence();
        int g = atomicAdd(gen, 0);
        if (atomicAdd(cnt, 1) == (int)gridDim.x - 1) {
            atomicExch(cnt, 0);
            __threadfence();
            atomicAdd(gen, 1);
        } else {
            while (atomicAdd(gen, 0) == g) __builtin_amdgcn_s_sleep(8);
        }
        __threadfence();
    }
    __syncthreads();
}

// ---- Phase F: XCD-partitioned padded-CSR fill | fp32->bf16 cast (slice-
// major [4][N][32]) | prepW (wave-coalesced Wsw). Work-stealing in chunks
// of 8 units. All 8 dst scan loads per thread upfront (one latency exposure).
__device__ void fill_phase(const int* __restrict__ edge, int E,
                           const float* __restrict__ att,
                           int* __restrict__ cursor, int* __restrict__ ovf_cnt,
                           unsigned int* __restrict__ pse, float4* __restrict__ ovf,
                           int rsize, int nfb,
                           const float* __restrict__ data,
                           unsigned short* __restrict__ data_bf, int n4, int cb, int NN,
                           const float* __restrict__ w1, unsigned short* __restrict__ w1s,
                           const float* __restrict__ w2, unsigned short* __restrict__ w2s,
                           int* __restrict__ ctr) {
    int t = threadIdx.x;
    __shared__ int s_or;
    __shared__ int s_b;
    if (t == 0) s_or = 0;
    __syncthreads();
    {
        int nw = 2 * E < 512 ? 2 * E : 512;
        int iw = t * 2 + 1;
        int vw = (iw < nw) ? edge[iw] : 0;
        if (vw != 0) atomicOr(&s_or, 1);
    }
    __syncthreads();
    int sh = (s_or == 0) ? 1 : 0;  // 1 => int64 stride, 0 => int32

    int totF = nfb + cb + 256;
    for (;;) {
        if (t == 0) s_b = atomicAdd(ctr, 8);
        __syncthreads();
        int b0 = s_b;
        if (b0 >= totF) break;
        int bend = min(b0 + 8, totF);
        for (int b1 = b0; b1 < bend; ++b1) {
            int b = b1;
            if (b < nfb) {
                int r = b & 7;
                int c = b >> 3;
                int lo = r * rsize;
                int hi = lo + rsize;
                int e0 = c * FCH;
                int ds[8];
#pragma unroll
                for (int k = 0; k < 8; ++k) {
                    int e = e0 + t + k * 256;
                    ds[k] = (e < E) ? edge[(size_t)(E + e) << sh] : -1;
                }
#pragma unroll
                for (int k = 0; k < 8; ++k) {
                    int d = ds[k];
                    if (d >= lo && d < hi) {
                        int e = e0 + t + k * 256;
                        int s = edge[(size_t)e << sh];
                        float a = att[e];
                        int slot = atomicAdd(&cursor[d], 1);
                        if (slot < CAP) {
                            unsigned int rec = ((unsigned int)f2bf(a) << 16) | (unsigned int)(s & 0xffff);
                            pse[(size_t)d * CAP + slot] = rec;
                        } else {
                            int oi = atomicAdd(ovf_cnt, 1);
                            ovf[oi] = make_float4(__int_as_float(d), __int_as_float(s), a, 0.f);
                        }
                    }
                }
                continue;
            }
            b -= nfb;
            if (b < cb) {
                int i = b * 256 + t;
                if (i < n4) {
                    float4 v = ((const float4*)data)[i];
                    ushort4 o;
                    o.x = f2bf(v.x); o.y = f2bf(v.y); o.z = f2bf(v.z); o.w = f2bf(v.w);
                    int nn = i >> 5;           // node
                    int c4 = i & 31;           // which float4 of the row (ch 4*c4)
                    *(ushort4*)(data_bf + (((size_t)(c4 >> 3) * NN + nn) << 5) + ((c4 & 7) << 2)) = o;
                }
                continue;
            }
            b -= cb;
            {
                const float* w = (b < 128) ? w1 : w2;
                unsigned short* wt = (b < 128) ? w1s : w2s;
                int bb = (b < 128) ? b : b - 128;
                int idx = bb * 256 + t;          // 0..32767
                int k = idx >> 7;                // 0..255
                int n = idx & 127;               // 0..127
                // wave-coalesced: gemm reads Wsw[((c*8+kc)*64+lane)*8+j]
                int c = n >> 4, l16 = n & 15;
                int kc = k >> 5, quad = (k >> 3) & 3, j = k & 7;
                int lane = quad * 16 + l16;
                size_t f = (((size_t)(c * 8 + kc) * 64 + lane) << 3) + j;
                wt[f] = f2bf(w[(size_t)k * 128 + n]);
            }
        }
        __syncthreads();   // before next grab overwrites s_b
    }
}

// ---- Phase A: channel-sliced aggregation, quad-per-node, 8-deep pipeline.
// Records staged ONCE per 64-node unit; inner loop over 4 slices. Steal 1.
__device__ void agg_phase(const unsigned short* __restrict__ x,
                          const unsigned int* __restrict__ pse,
                          const int* __restrict__ cursor,
                          const int* __restrict__ ovf_cnt,
                          const float4* __restrict__ ovf,
                          unsigned short* __restrict__ agg, int N,
                          int* __restrict__ ctr) {
    __shared__ __align__(16) unsigned int s_rec[64 * 36];   // 9216 B
    __shared__ int s_u;
    int tid = threadIdx.x;
    int nbk = (N + 63) >> 6;
    int lane = tid & 63;
    int wave = tid >> 6;
    int q = lane >> 2;            // quad -> node within wave
    int l4 = lane & 3;            // 16B sub-segment of the 64B slice row
    int oc = ovf_cnt[0];

    for (;;) {
        if (tid == 0) s_u = atomicAdd(ctr, 1);
        __syncthreads();
        int u = s_u;
        if (u >= nbk) break;
        int base = u * 64;
#pragma unroll
        for (int k = 0; k < 2; ++k) {
            int idx4 = tid + k * 256;        // 0..511
            int i = idx4 >> 3;               // node local 0..63
            int j0 = (idx4 & 7) << 2;        // slot 0,4,...,28
            int nn = base + i;
            uint4 v = make_uint4(0u, 0u, 0u, 0u);
            if (nn < N) v = *(const uint4*)(pse + ((size_t)nn << 5) + j0);
            *(uint4*)(&s_rec[i * 36 + j0]) = v;
        }
        __syncthreads();

        int ni = wave * 16 + q;       // node local 0..63
        int n = base + ni;
        bool valid = n < N;
        int deg = valid ? cursor[n] : 0;
        int m = min(deg, CAP);
        const unsigned int* rp = &s_rec[ni * 36];
        float inv = 1.0f / fmaxf((float)deg, 1.0f);

        for (int pass = 0; pass < 4; ++pass) {
            const unsigned short* xs = x + (((size_t)pass * N) << 5) + (l4 << 3);
            float s[8] = {0.f, 0.f, 0.f, 0.f, 0.f, 0.f, 0.f, 0.f};

            unsigned int rr[8];
#pragma unroll
            for (int k = 0; k < 8; ++k) {
                unsigned int r = rp[k];
                rr[k] = (k < m) ? r : 0u;          // rec=0 -> row0, att=0
            }
            for (int j = 0; j < m; j += 8) {
                uint4 uu[8];
#pragma unroll
                for (int k = 0; k < 8; ++k)
                    uu[k] = *(const uint4*)(xs + ((size_t)(rr[k] & 0xffffu) << 5));
                unsigned int rn[8];
#pragma unroll
                for (int k = 0; k < 8; ++k) {
                    int jn = j + 8 + k;
                    rn[k] = (jn < m) ? rp[jn] : 0u;   // in padded row, safe
                }
#pragma unroll
                for (int k = 0; k < 8; ++k)
                    acc8(uu[k], __uint_as_float(rr[k] & 0xffff0000u), s);
#pragma unroll
                for (int k = 0; k < 8; ++k) rr[k] = rn[k];
            }

            if (oc > 0 && valid) {     // overflow path (normally skipped)
                for (int k = 0; k < oc; ++k) {
                    float4 f = ovf[k];
                    if (__float_as_int(f.x) == n) {
                        uint4 u2 = *(const uint4*)(xs + ((size_t)__float_as_int(f.y) << 5));
                        acc8(u2, f.z, s);
                    }
                }
            }

            if (valid) {
                uint4 o;
                o.x = (unsigned int)f2bf(s[0] * inv) | ((unsigned int)f2bf(s[1] * inv) << 16);
                o.y = (unsigned int)f2bf(s[2] * inv) | ((unsigned int)f2bf(s[3] * inv) << 16);
                o.z = (unsigned int)f2bf(s[4] * inv) | ((unsigned int)f2bf(s[5] * inv) << 16);
                o.w = (unsigned int)f2bf(s[6] * inv) | ((unsigned int)f2bf(s[7] * inv) << 16);
                *(uint4*)(agg + ((((size_t)pass * N) + n) << 5) + (l4 << 3)) = o;
            }
        }
        __syncthreads();   // before next grab overwrites s_u / s_rec
    }
}

// ---- Phase G: out[M,128] = relu([X|AGG][M,256]bf16 @ W + b), MFMA 16x16x32.
// X/AGG slice-major [4][M][32]. B-frags streamed from global Wsw (L2-resident,
// wave-coalesced 1KB/instr). No W LDS. C/D: col=lane&15, row=quad*4+reg.
__device__ void gemm_phase(const unsigned short* __restrict__ X,
                           const unsigned short* __restrict__ AGG,
                           const unsigned short* __restrict__ Wsw,
                           const float* __restrict__ bias,
                           float* __restrict__ outF,
                           unsigned short* __restrict__ outB, int M,
                           int* __restrict__ ctr) {
    __shared__ int s_u;
    int tid = threadIdx.x;
    int wave = tid >> 6;
    int lane = tid & 63;
    int l16 = lane & 15;
    int quad = lane >> 4;
    int nbk = (M + 63) >> 6;

    for (;;) {
        if (tid == 0) s_u = atomicAdd(ctr, 1);
        __syncthreads();
        int u = s_u;
        if (u >= nbk) break;

        int row = u * 64 + wave * 16 + l16;
        int rowA = min(row, M - 1);
        const unsigned short* xb0 = X + ((size_t)rowA << 5) + quad * 8;
        const unsigned short* ab0 = AGG + ((size_t)rowA << 5) + quad * 8;
        bf16x8 af[8];
#pragma unroll
        for (int kc = 0; kc < 4; ++kc) af[kc] = *(const bf16x8*)(xb0 + (((size_t)kc * M) << 5));
#pragma unroll
        for (int kc = 0; kc < 4; ++kc) af[kc + 4] = *(const bf16x8*)(ab0 + (((size_t)kc * M) << 5));

        floatx4 acc[8];
#pragma unroll
        for (int c = 0; c < 8; ++c) acc[c] = (floatx4){0.f, 0.f, 0.f, 0.f};

#pragma unroll
        for (int kc = 0; kc < 8; ++kc) {
#pragma unroll
            for (int c = 0; c < 8; ++c) {
                bf16x8 bfr = *(const bf16x8*)(Wsw + (((size_t)(c * 8 + kc) * 64 + lane) << 3));
                acc[c] = __builtin_amdgcn_mfma_f32_16x16x32_bf16(af[kc], bfr, acc[c], 0, 0, 0);
            }
        }

        int orow0 = u * 64 + wave * 16 + quad * 4;
#pragma unroll
        for (int c = 0; c < 8; ++c) {
            int col = c * 16 + l16;
            float bv = bias[col];
#pragma unroll
            for (int r = 0; r < 4; ++r) {
                int orow = orow0 + r;
                if (orow < M) {
                    float v = fmaxf(acc[c][r] + bv, 0.f);
                    if (outF) outF[(size_t)orow * 128 + col] = v;
                    else outB[(((size_t)(col >> 5) * M + orow) << 5) + (col & 31)] = f2bf(v);
                }
            }
        }
        __syncthreads();   // before next grab overwrites s_u
    }
}

// ---- Single persistent mega-kernel: 5 phases, 4 hand-rolled grid barriers.
// bar = {count, gen}; wk = 5 per-phase work-steal counters. All zeroed by
// the host memset. 2 blocks/CU guaranteed by __launch_bounds__(256,2).
__global__ __launch_bounds__(256, 2) void k_mega(const int* edge, int E, const float* att,
                                                 int* cursor, int* ovf_cnt,
                                                 unsigned int* pse, float4* ovf,
                                                 int rsize, int nfb,
                                                 const float* data, unsigned short* data_bf,
                                                 int n4, int cb, int N,
                                                 const float* w1, unsigned short* w1s,
                                                 const float* w2, unsigned short* w2s,
                                                 const float* b1, const float* b2,
                                                 unsigned short* agg_bf, unsigned short* out1_bf,
                                                 float* outF, int* bar, int* wk) {
    fill_phase(edge, E, att, cursor, ovf_cnt, pse, ovf, rsize, nfb,
               data, data_bf, n4, cb, N, w1, w1s, w2, w2s, &wk[0]);
    grid_sync(&bar[0], &bar[1]);

    agg_phase(data_bf, pse, cursor, ovf_cnt, ovf, agg_bf, N, &wk[1]);
    grid_sync(&bar[0], &bar[1]);

    gemm_phase(data_bf, agg_bf, w1s, b1, nullptr, out1_bf, N, &wk[2]);
    grid_sync(&bar[0], &bar[1]);

    agg_phase(out1_bf, pse, cursor, ovf_cnt, ovf, agg_bf, N, &wk[3]);
    grid_sync(&bar[0], &bar[1]);

    gemm_phase(out1_bf, agg_bf, w2s, b2, outF, nullptr, N, &wk[4]);
}

extern "C" void kernel_launch(void* const* d_in, const int* in_sizes, int n_in,
                              void* d_out, int out_size, void* d_ws, size_t ws_size,
                              hipStream_t stream) {
    const float* data = (const float*)d_in[0];
    const int* edge = (const int*)d_in[1];
    const float* att = (const float*)d_in[2];
    const float* w1 = (const float*)d_in[3];
    const float* b1 = (const float*)d_in[4];
    const float* w2 = (const float*)d_in[5];
    const float* b2 = (const float*)d_in[6];

    int N = in_sizes[0] / HDIM;
    int E = in_sizes[1] / 2;

    char* ws = (char*)d_ws;
    size_t o = 0;
    auto carve = [&](size_t bytes) -> char* {
        char* r = ws + o;
        o = (o + bytes + 255) & ~(size_t)255;
        return r;
    };
    // cursor[N] | ovf_cnt at [N] | bar at [N+4..N+5] | wk at [N+8..N+12]
    int* cursor = (int*)carve((size_t)(N + 16) * 4);
    int* ovf_cnt = cursor + N;
    int* bar = cursor + N + 4;
    int* wk = cursor + N + 8;
    unsigned int* pse = (unsigned int*)carve((size_t)N * CAP * 4);  // 4B records
    float4* ovf = (float4*)carve((size_t)E * 16);             // overflow (usually empty)
    unsigned short* data_bf = (unsigned short*)carve((size_t)N * 128 * 2);
    unsigned short* w1s = (unsigned short*)carve(256 * 128 * 2);
    unsigned short* w2s = (unsigned short*)carve(256 * 128 * 2);
    unsigned short* agg_bf = (unsigned short*)carve((size_t)N * 128 * 2);
    unsigned short* out1_bf = (unsigned short*)carve((size_t)N * 128 * 2);
    float* outF = (float*)d_out;

    // Zero cursor + ovf + barrier + work-steal counters (capture-safe).
    hipMemsetAsync(cursor, 0, (size_t)(N + 16) * 4, stream);

    int rsize = (N + 7) / 8;
    int nch = (E + FCH - 1) / FCH;
    int nfb = nch * 8;
    int n4 = N * 32;
    int cb = (n4 + 255) / 256;

    k_mega<<<dim3(NBLK), dim3(256), 0, stream>>>(edge, E, att, cursor, ovf_cnt, pse, ovf,
                                                 rsize, nfb, data, data_bf, n4, cb, N,
                                                 w1, w1s, w2, w2s, b1, b2,
                                                 agg_bf, out1_bf, outF, bar, wk);
}

// Round 7
// 206.094 us; speedup vs baseline: 3.0916x; 3.0916x over previous
//
#include <hip/hip_runtime.h>

// GNN: 2 x (SimpleConv(mean, cat) -> Linear(256->128) -> ReLU)
// N=50000 nodes, E=640000 edges, H=128.
//
// R1-R14: CSR pipeline, bf16, MFMA gemm, 5 kernels + memset. 209.7us.
// R15: slice-major [4][N][32]; agg FETCH compulsory but VALU-bound. 310.
// R16: quad-per-node serial gather. 221.4. R17: fill single-pass REGRESSED
//      (lost XCD partition); agg 8-deep batches. 215.5.
// R18: fill partition + 8 upfront scan loads; agg sw-pipeline. 214.2.
// R19 ACCOUNTING: ~77us = 6 dispatch gaps (~13us each), 36% of wall.
// R20 FAILED: cooperative launch broke graph capture.
// R21 REGRESSED 594us: persistent mega forced ALL phases to 8 waves/CU
//      (OccupancyPercent 24); latency-bound fill/agg lost 3-4x latency
//      hiding. Lesson: persistence pins every phase to worst-case occupancy.
//      (Wsw wave-coalesced L2-streamed gemm B-path validated correct here.)
// R22: fuse ONLY block-local deps: agg+gemm share the 64-row tile, so
//      k_layer = agg -> LDS tile [64][136]bf16 (272B padded rows, balanced
//      bank groups) -> gemm, normal 782-block dispatch, no grid sync.
//      16-deep gather batch (avg deg 12.8 -> ~1 latency exposure/node/pass)
//      compensates 32->16 waves/CU. W from L2 (Wsw). 4 dispatches total:
//      memset | fill+cast+prepW | layer1 | layer2. Kills 2 gaps (~26us)
//      + agg_bf HBM round-trip (~8us).

#define HDIM 128
#define CAP 32            // padded CSR slots/node; P(deg>32 | Poisson 12.8) ~ 2e-6
#define FCH 2048          // edges per fill chunk

typedef __bf16 bf16x8 __attribute__((ext_vector_type(8)));
typedef float floatx4 __attribute__((ext_vector_type(4)));

__device__ __forceinline__ unsigned short f2bf(float f) {
    unsigned int u = __float_as_uint(f);
    unsigned int r = (u + 0x7fff + ((u >> 16) & 1)) >> 16;   // RNE
    return (unsigned short)r;
}
__device__ __forceinline__ float bf2f(unsigned short b) {
    return __uint_as_float((unsigned int)b << 16);
}
__device__ __forceinline__ void acc8(const uint4& u, float a, float* s) {
    s[0] = fmaf(bf2f((unsigned short)(u.x & 0xffff)), a, s[0]);
    s[1] = fmaf(bf2f((unsigned short)(u.x >> 16)), a, s[1]);
    s[2] = fmaf(bf2f((unsigned short)(u.y & 0xffff)), a, s[2]);
    s[3] = fmaf(bf2f((unsigned short)(u.y >> 16)), a, s[3]);
    s[4] = fmaf(bf2f((unsigned short)(u.z & 0xffff)), a, s[4]);
    s[5] = fmaf(bf2f((unsigned short)(u.z >> 16)), a, s[5]);
    s[6] = fmaf(bf2f((unsigned short)(u.w & 0xffff)), a, s[6]);
    s[7] = fmaf(bf2f((unsigned short)(u.w >> 16)), a, s[7]);
}

// Fused: XCD-partitioned padded-CSR fill | fp32->bf16 cast (slice-major
// [4][N][32]) | prepW (wave-coalesced Wsw for L2-streamed gemm B-frags).
// Fill blocks [0,nfb): block b -> edge chunk (b>>3), dst range (b&7);
// all 8 dst scan loads upfront (one latency exposure).
__global__ __launch_bounds__(256) void k_fill(const int* __restrict__ edge, int E,
                                              const float* __restrict__ att,
                                              int* __restrict__ cursor,
                                              int* __restrict__ ovf_cnt,
                                              unsigned int* __restrict__ pse,
                                              float4* __restrict__ ovf, int rsize,
                                              int nfb,
                                              const float* __restrict__ data,
                                              unsigned short* __restrict__ data_bf, int n4,
                                              int cb, int NN,
                                              const float* __restrict__ w1,
                                              unsigned short* __restrict__ w1s,
                                              const float* __restrict__ w2,
                                              unsigned short* __restrict__ w2s) {
    int b = blockIdx.x;
    int t = threadIdx.x;
    if (b < nfb) {
        __shared__ int s_or;
        if (t == 0) s_or = 0;
        __syncthreads();
        int nw = 2 * E < 512 ? 2 * E : 512;
        int iw = t * 2 + 1;
        int vw = (iw < nw) ? edge[iw] : 0;
        if (vw != 0) atomicOr(&s_or, 1);
        __syncthreads();
        int sh = (s_or == 0) ? 1 : 0;  // 1 => int64 stride, 0 => int32

        int r = b & 7;
        int c = b >> 3;
        int lo = r * rsize;
        int hi = lo + rsize;
        int e0 = c * FCH;
        int ds[8];
#pragma unroll
        for (int k = 0; k < 8; ++k) {
            int e = e0 + t + k * 256;
            ds[k] = (e < E) ? edge[(size_t)(E + e) << sh] : -1;
        }
#pragma unroll
        for (int k = 0; k < 8; ++k) {
            int d = ds[k];
            if (d >= lo && d < hi) {
                int e = e0 + t + k * 256;
                int s = edge[(size_t)e << sh];
                float a = att[e];
                int slot = atomicAdd(&cursor[d], 1);
                if (slot < CAP) {
                    unsigned int rec = ((unsigned int)f2bf(a) << 16) | (unsigned int)(s & 0xffff);
                    pse[(size_t)d * CAP + slot] = rec;
                } else {
                    int oi = atomicAdd(ovf_cnt, 1);
                    ovf[oi] = make_float4(__int_as_float(d), __int_as_float(s), a, 0.f);
                }
            }
        }
        return;
    }
    b -= nfb;
    if (b < cb) {
        int i = b * 256 + t;
        if (i < n4) {
            float4 v = ((const float4*)data)[i];
            ushort4 o;
            o.x = f2bf(v.x); o.y = f2bf(v.y); o.z = f2bf(v.z); o.w = f2bf(v.w);
            int nn = i >> 5;           // node
            int c4 = i & 31;           // which float4 of the row (ch 4*c4)
            // slice-major: [slice][N][32]
            *(ushort4*)(data_bf + (((size_t)(c4 >> 3) * NN + nn) << 5) + ((c4 & 7) << 2)) = o;
        }
        return;
    }
    b -= cb;
    {
        const float* w = (b < 128) ? w1 : w2;
        unsigned short* wt = (b < 128) ? w1s : w2s;
        int bb = (b < 128) ? b : b - 128;
        int idx = bb * 256 + t;          // 0..32767
        int k = idx >> 7;                // 0..255
        int n = idx & 127;               // 0..127
        // wave-coalesced: gemm reads Wsw[((c*8+kc)*64+lane)*8+j]  (R21-validated)
        int c = n >> 4, l16 = n & 15;
        int kc = k >> 5, quad = (k >> 3) & 3, j = k & 7;
        int lane = quad * 16 + l16;
        size_t f = (((size_t)(c * 8 + kc) * 64 + lane) << 3) + j;
        wt[f] = f2bf(w[(size_t)k * 128 + n]);
    }
}

// Fused layer: agg (quad-per-node, 4 channel slices, 16-deep gather batch)
// -> LDS tile s_agg[64][136] bf16 -> MFMA gemm for the SAME 64 rows.
// x slice-major [4][M][32] bf16. Block = 256 thr, one 64-node unit.
// Wsw streamed from L2 (1KB/frag/wave). outB (layer1) slice-major bf16;
// outF (layer2) row-major f32.
__global__ __launch_bounds__(256, 4) void k_layer(const unsigned short* __restrict__ x,
                                                  const unsigned int* __restrict__ pse,
                                                  const int* __restrict__ cursor,
                                                  const int* __restrict__ ovf_cnt,
                                                  const float4* __restrict__ ovf,
                                                  const unsigned short* __restrict__ Wsw,
                                                  const float* __restrict__ bias,
                                                  float* __restrict__ outF,
                                                  unsigned short* __restrict__ outB,
                                                  int M) {
    __shared__ __align__(16) unsigned int s_rec[64 * 36];      //  9216 B
    __shared__ __align__(16) unsigned short s_agg[64 * 136];   // 17408 B (272B rows)
    int tid = threadIdx.x;
    int base = blockIdx.x * 64;

    // Stage 64 nodes x 32 records (uint4-vectorized, coalesced).
#pragma unroll
    for (int k = 0; k < 2; ++k) {
        int idx4 = tid + k * 256;        // 0..511
        int i = idx4 >> 3;               // node local 0..63
        int j0 = (idx4 & 7) << 2;        // slot 0,4,...,28
        int nn = base + i;
        uint4 v = make_uint4(0u, 0u, 0u, 0u);
        if (nn < M) v = *(const uint4*)(pse + ((size_t)nn << 5) + j0);
        *(uint4*)(&s_rec[i * 36 + j0]) = v;
    }
    __syncthreads();

    int lane = tid & 63;
    int wave = tid >> 6;
    int q = lane >> 2;            // quad -> node within wave
    int l4 = lane & 3;            // 16B sub-segment of the 64B slice row
    int ni = wave * 16 + q;       // node local 0..63
    int n = base + ni;
    bool valid = n < M;
    int deg = valid ? cursor[n] : 0;
    int m = min(deg, CAP);
    const unsigned int* rp = &s_rec[ni * 36];
    float inv = 1.0f / fmaxf((float)deg, 1.0f);
    int oc = ovf_cnt[0];

    for (int pass = 0; pass < 4; ++pass) {
        const unsigned short* xs = x + (((size_t)pass * M) << 5) + (l4 << 3);
        float s[8] = {0.f, 0.f, 0.f, 0.f, 0.f, 0.f, 0.f, 0.f};

        for (int j = 0; j < m; j += 16) {       // 16 gathers in flight
            unsigned int rr[16];
#pragma unroll
            for (int k = 0; k < 16; ++k) {
                unsigned int r = rp[j + k];          // padded row (36), j+k<=31
                rr[k] = (j + k < m) ? r : 0u;        // rec=0 -> row0, att=0
            }
            uint4 uu[16];
#pragma unroll
            for (int k = 0; k < 16; ++k)
                uu[k] = *(const uint4*)(xs + ((size_t)(rr[k] & 0xffffu) << 5));
#pragma unroll
            for (int k = 0; k < 16; ++k)
                acc8(uu[k], __uint_as_float(rr[k] & 0xffff0000u), s);
        }

        if (oc > 0 && valid) {     // overflow path (normally skipped)
            for (int k = 0; k < oc; ++k) {
                float4 f = ovf[k];
                if (__float_as_int(f.x) == n) {
                    uint4 u2 = *(const uint4*)(xs + ((size_t)__float_as_int(f.y) << 5));
                    acc8(u2, f.z, s);
                }
            }
        }

        // Write 8 ch (16B) to the block-local agg tile (invalid rows -> 0).
        uint4 o;
        o.x = (unsigned int)f2bf(s[0] * inv) | ((unsigned int)f2bf(s[1] * inv) << 16);
        o.y = (unsigned int)f2bf(s[2] * inv) | ((unsigned int)f2bf(s[3] * inv) << 16);
        o.z = (unsigned int)f2bf(s[4] * inv) | ((unsigned int)f2bf(s[5] * inv) << 16);
        o.w = (unsigned int)f2bf(s[6] * inv) | ((unsigned int)f2bf(s[7] * inv) << 16);
        *(uint4*)(&s_agg[ni * 136 + pass * 32 + l4 * 8]) = o;
    }
    __syncthreads();

    // ---- gemm: out[64,128] = relu([X | s_agg] @ W + b), MFMA 16x16x32.
    int l16 = lane & 15;
    int quad = lane >> 4;
    int row = base + wave * 16 + l16;
    int rowA = min(row, M - 1);
    int lrow = wave * 16 + l16;                 // local row in s_agg
    const unsigned short* xb0 = x + ((size_t)rowA << 5) + quad * 8;
    bf16x8 af[8];
#pragma unroll
    for (int kc = 0; kc < 4; ++kc) af[kc] = *(const bf16x8*)(xb0 + (((size_t)kc * M) << 5));
#pragma unroll
    for (int kc = 0; kc < 4; ++kc)
        af[kc + 4] = *(const bf16x8*)(&s_agg[lrow * 136 + kc * 32 + quad * 8]);

    floatx4 acc[8];
#pragma unroll
    for (int c = 0; c < 8; ++c) acc[c] = (floatx4){0.f, 0.f, 0.f, 0.f};

#pragma unroll
    for (int kc = 0; kc < 8; ++kc) {
#pragma unroll
        for (int c = 0; c < 8; ++c) {
            bf16x8 bfr = *(const bf16x8*)(Wsw + (((size_t)(c * 8 + kc) * 64 + lane) << 3));
            acc[c] = __builtin_amdgcn_mfma_f32_16x16x32_bf16(af[kc], bfr, acc[c], 0, 0, 0);
        }
    }

    int orow0 = base + wave * 16 + quad * 4;
#pragma unroll
    for (int c = 0; c < 8; ++c) {
        int col = c * 16 + l16;
        float bv = bias[col];
#pragma unroll
        for (int r = 0; r < 4; ++r) {
            int orow = orow0 + r;
            if (orow < M) {
                float v = fmaxf(acc[c][r] + bv, 0.f);
                if (outF) outF[(size_t)orow * 128 + col] = v;
                else outB[(((size_t)(col >> 5) * M + orow) << 5) + (col & 31)] = f2bf(v);
            }
        }
    }
}

extern "C" void kernel_launch(void* const* d_in, const int* in_sizes, int n_in,
                              void* d_out, int out_size, void* d_ws, size_t ws_size,
                              hipStream_t stream) {
    const float* data = (const float*)d_in[0];
    const int* edge = (const int*)d_in[1];
    const float* att = (const float*)d_in[2];
    const float* w1 = (const float*)d_in[3];
    const float* b1 = (const float*)d_in[4];
    const float* w2 = (const float*)d_in[5];
    const float* b2 = (const float*)d_in[6];

    const int N = in_sizes[0] / HDIM;
    const int E = in_sizes[1] / 2;

    char* ws = (char*)d_ws;
    size_t o = 0;
    auto carve = [&](size_t bytes) -> char* {
        char* r = ws + o;
        o = (o + bytes + 255) & ~(size_t)255;
        return r;
    };
    int* cursor = (int*)carve((size_t)(N + 4) * 4);   // cursor[N] + ovf_cnt at [N]
    int* ovf_cnt = cursor + N;
    unsigned int* pse = (unsigned int*)carve((size_t)N * CAP * 4);  // 4B records
    float4* ovf = (float4*)carve((size_t)E * 16);             // overflow (usually empty)
    unsigned short* data_bf = (unsigned short*)carve((size_t)N * 128 * 2);
    unsigned short* w1s = (unsigned short*)carve(256 * 128 * 2);
    unsigned short* w2s = (unsigned short*)carve(256 * 128 * 2);
    unsigned short* out1_bf = (unsigned short*)carve((size_t)N * 128 * 2);
    float* outF = (float*)d_out;

    // Zero cursor+ovf counters (stream-ordered, graph-capture-safe).
    hipMemsetAsync(cursor, 0, (size_t)(N + 4) * 4, stream);

    int rsize = (N + 7) / 8;
    int nch = (E + FCH - 1) / FCH;
    int nfb = nch * 8;
    int n4 = N * 32;
    int cb = (n4 + 255) / 256;
    k_fill<<<nfb + cb + 256, 256, 0, stream>>>(edge, E, att, cursor, ovf_cnt, pse, ovf,
                                               rsize, nfb, data, data_bf, n4, cb, N,
                                               w1, w1s, w2, w2s);

    int nbk = (N + 63) / 64;
    // Layer 1: agg+gemm fused (agg tile via LDS), bf16 slice-major out.
    k_layer<<<nbk, 256, 0, stream>>>(data_bf, pse, cursor, ovf_cnt, ovf,
                                     w1s, b1, nullptr, out1_bf, N);
    // Layer 2: agg+gemm fused, f32 row-major out.
    k_layer<<<nbk, 256, 0, stream>>>(out1_bf, pse, cursor, ovf_cnt, ovf,
                                     w2s, b2, outF, nullptr, N);
}